// Round 2
// baseline (232.432 us; speedup 1.0000x reference)
//
#include <hip/hip_runtime.h>
#include <math.h>

#define BATCH 4096
#define NFEAT 4
#define VOCAB 100000
#define EMB 64
#define D_O 128
#define ROWS 16            // user rows per block
#define TROWS 48           // 16 user + 32 item rows (item tile rounded to 2 M-tiles)
#define LIVE_ROWS 35       // 16 user + 19 item rows actually gathered/used
#define XS_STRIDE 264      // ushort stride: 528 B/row == 132 floats (16B aligned)
#define YS_F_STRIDE 132    // float stride when Xs buffer is aliased as fp32

typedef __attribute__((ext_vector_type(8))) short bf16x8;
typedef __attribute__((ext_vector_type(4))) float f32x4;

__device__ inline ushort f2bf(float f) {
  union { float f; unsigned u; } v; v.f = f;
  unsigned u = v.u;
  return (ushort)((u + 0x7fffu + ((u >> 16) & 1u)) >> 16);  // RNE
}

// ---------------------------------------------------------------------------
// Prep: transpose + convert the four weight matrices to bf16 Wt[n][k].
// ---------------------------------------------------------------------------
__global__ __launch_bounds__(256) void prep_kernel(
    const float* __restrict__ uW1, const float* __restrict__ uW2,
    const float* __restrict__ iW1, const float* __restrict__ iW2,
    ushort* __restrict__ W1tu, ushort* __restrict__ W2tu,
    ushort* __restrict__ W1ti, ushort* __restrict__ W2ti) {
  int idx = blockIdx.x * 256 + threadIdx.x;  // 0 .. 196608
  if (idx < 65536) {
    int n = idx >> 8, k = idx & 255;
    W1tu[idx] = f2bf(uW1[k * 256 + n]);
  } else if (idx < 131072) {
    int j = idx - 65536; int n = j >> 8, k = j & 255;
    W1ti[j] = f2bf(iW1[k * 256 + n]);
  } else if (idx < 163840) {
    int j = idx - 131072; int n = j >> 8, k = j & 255;
    W2tu[j] = f2bf(uW2[k * 128 + n]);
  } else {
    int j = idx - 163840; int n = j >> 8, k = j & 255;
    W2ti[j] = f2bf(iW2[k * 128 + n]);
  }
}

// ---------------------------------------------------------------------------
// Fully fused: gather(user 16 rows + item 19 rows) -> L1 -> L2 -> normalize
// -> in-block score. One block per 16 output rows; item rows i..i+18 are
// computed redundantly per block so no cross-block dependency exists.
// MFMA 16x16x32 fragment mapping (verified layout):
//   A-frag: lane holds A[m=lane&15][k=quad*8+j]
//   B-frag: lane holds B[k=quad*8+j][n=lane&15]  (read from Wt[n][k] contiguously)
//   C/D   : lane holds D[row=quad*4+reg][col=lane&15]
// ---------------------------------------------------------------------------
__global__ __launch_bounds__(256) void fused_kernel(
    const int* __restrict__ user_ids, const int* __restrict__ item_ids,
    const int* __restrict__ sw_ids,
    const float* __restrict__ user_tables, const float* __restrict__ item_tables,
    const float* __restrict__ sw_table,
    const ushort* __restrict__ W1tu, const float* __restrict__ ub1,
    const ushort* __restrict__ W2tu, const float* __restrict__ ub2,
    const ushort* __restrict__ W1ti, const float* __restrict__ ib1,
    const ushort* __restrict__ W2ti, const float* __restrict__ ib2,
    float* __restrict__ out) {
  const int r0 = blockIdx.x * ROWS;
  const int tid = threadIdx.x;
  const int lane = tid & 63;
  const int w = tid >> 6;
  const int m = lane & 15;
  const int quad = lane >> 4;

  // Xs buffer is reused: bf16 gather input (phases 1-2), then fp32 Y output
  // (phases 3-5). Row strides match: 264 ushorts == 132 floats == 528 B.
  __shared__ __align__(16) char XsRaw[TROWS * XS_STRIDE * 2];  // 25.3 KB
  __shared__ ushort Hs[TROWS][XS_STRIDE];                      // 25.3 KB
  __shared__ float Lsw[32];                                    // log(sw) per item col
  ushort* Xs = (ushort*)XsRaw;
  float* Yf = (float*)XsRaw;

  // ---- phase 0: log sample-weights for the 19 item columns of this block
  if (tid < 19) {
    int c = (r0 + tid) & (BATCH - 1);
    Lsw[tid] = logf(sw_table[sw_ids[c]]);
  }

  // ---- phase 1: gather LIVE_ROWS x 256 floats -> bf16 Xs.
  // slot = row*64 + c4 ; row uniform per wave per iteration (64 slots/row).
#pragma unroll
  for (int i = 0; i < 9; i++) {
    int slot = i * 256 + tid;
    if (slot < LIVE_ROWS * 64) {
      int row = slot >> 6;
      int c4 = slot & 63;
      int f = c4 >> 4;
      const int* ids = (row < ROWS) ? user_ids : item_ids;
      const float* tab = (row < ROWS) ? user_tables : item_tables;
      int grow = (row < ROWS) ? (r0 + row) : ((r0 + row - ROWS) & (BATCH - 1));
      int id = ids[grow * NFEAT + f];
      float4 v = ((const float4*)(tab + ((size_t)f * VOCAB + (size_t)id) * EMB))[c4 & 15];
      ushort4 o = {f2bf(v.x), f2bf(v.y), f2bf(v.z), f2bf(v.w)};
      *(ushort4*)&Xs[row * XS_STRIDE + c4 * 4] = o;
    }
  }
  // zero-fill dead rows 35..47 so no phase reads uninitialized LDS
  for (int s = LIVE_ROWS * 64 + tid; s < TROWS * 64; s += 256) {
    int row = s >> 6;
    int c4 = s & 63;
    ushort4 z = {0, 0, 0, 0};
    *(ushort4*)&Xs[row * XS_STRIDE + c4 * 4] = z;
  }
  __syncthreads();

  // ---- phase 2: L1 (256->256 relu) for 3 M-tiles: user, item lo, item hi.
#pragma unroll
  for (int mt = 0; mt < 3; mt++) {
    const ushort* W1t = mt ? W1ti : W1tu;
    const float* b1 = mt ? ib1 : ub1;
    bf16x8 a[8];
#pragma unroll
    for (int k0 = 0; k0 < 8; k0++)
      a[k0] = *(const bf16x8*)&Xs[(mt * 16 + m) * XS_STRIDE + k0 * 32 + quad * 8];
#pragma unroll
    for (int ct = 0; ct < 4; ct++) {
      int n = (w * 4 + ct) * 16 + m;
      const ushort* wp = W1t + (size_t)n * 256 + quad * 8;
      f32x4 acc = {0.f, 0.f, 0.f, 0.f};
#pragma unroll
      for (int k0 = 0; k0 < 8; k0++)
        acc = __builtin_amdgcn_mfma_f32_16x16x32_bf16(
            a[k0], *(const bf16x8*)(wp + k0 * 32), acc, 0, 0, 0);
      float bias = b1[n];
#pragma unroll
      for (int reg = 0; reg < 4; reg++)
        Hs[mt * 16 + quad * 4 + reg][n] = f2bf(fmaxf(acc[reg] + bias, 0.f));
    }
  }
  __syncthreads();

  // ---- phase 3: L2 (256->128 relu) -> Yf (aliased onto dead Xs buffer).
  // Phase 3 only READS Hs and WRITES Yf/Xs -> no intra-phase hazard.
#pragma unroll
  for (int mt = 0; mt < 3; mt++) {
    const ushort* W2t = mt ? W2ti : W2tu;
    const float* b2 = mt ? ib2 : ub2;
    bf16x8 h[8];
#pragma unroll
    for (int k0 = 0; k0 < 8; k0++)
      h[k0] = *(const bf16x8*)&Hs[mt * 16 + m][k0 * 32 + quad * 8];
#pragma unroll
    for (int ct = 0; ct < 2; ct++) {
      int n = (w * 2 + ct) * 16 + m;
      const ushort* wp = W2t + (size_t)n * 256 + quad * 8;
      f32x4 acc = {0.f, 0.f, 0.f, 0.f};
#pragma unroll
      for (int k0 = 0; k0 < 8; k0++)
        acc = __builtin_amdgcn_mfma_f32_16x16x32_bf16(
            h[k0], *(const bf16x8*)(wp + k0 * 32), acc, 0, 0, 0);
      float bias = b2[n];
#pragma unroll
      for (int reg = 0; reg < 4; reg++)
        Yf[(mt * 16 + quad * 4 + reg) * YS_F_STRIDE + n] =
            fmaxf(acc[reg] + bias, 0.f);
    }
  }
  __syncthreads();

  // ---- phase 4: row L2-normalize in place (48 rows, 12 per wave).
  // Rows >= 35 normalize zeros; never read afterwards.
#pragma unroll
  for (int rr = 0; rr < 12; rr++) {
    int row = w * 12 + rr;
    float y0 = Yf[row * YS_F_STRIDE + lane];
    float y1 = Yf[row * YS_F_STRIDE + 64 + lane];
    float s = y0 * y0 + y1 * y1;
#pragma unroll
    for (int off = 32; off; off >>= 1) s += __shfl_xor(s, off);
    float inv = 1.f / fmaxf(sqrtf(s), 1e-8f);
    Yf[row * YS_F_STRIDE + lane] = y0 * inv;
    Yf[row * YS_F_STRIDE + 64 + lane] = y1 * inv;
  }
  __syncthreads();

  // ---- phase 5: score. out[r0+i][j] = dot(un_i, vn_{i+j}) - log(sw[c]).
  // un rows: Yf[0..15]; vn rows: Yf[16..34] (local item rows 0..18).
#pragma unroll
  for (int rr = 0; rr < 4; rr++) {
    int i = w * 4 + rr;  // local user row
    float u0 = Yf[i * YS_F_STRIDE + lane];
    float u1 = Yf[i * YS_F_STRIDE + 64 + lane];
#pragma unroll
    for (int j = 0; j < 4; j++) {
      int vrow = ROWS + i + j;  // local item row i+j
      float v0 = Yf[vrow * YS_F_STRIDE + lane];
      float v1 = Yf[vrow * YS_F_STRIDE + 64 + lane];
      float d = u0 * v0 + u1 * v1;
#pragma unroll
      for (int off = 32; off; off >>= 1) d += __shfl_xor(d, off);
      if (lane == 0) out[(size_t)(r0 + i) * 4 + j] = d - Lsw[i + j];
    }
  }
}

extern "C" void kernel_launch(void* const* d_in, const int* in_sizes, int n_in,
                              void* d_out, int out_size, void* d_ws, size_t ws_size,
                              hipStream_t stream) {
  (void)in_sizes; (void)n_in; (void)out_size; (void)ws_size;
  const int*   user_ids    = (const int*)d_in[0];
  const int*   item_ids    = (const int*)d_in[1];
  const int*   sw_ids      = (const int*)d_in[2];
  const float* user_tables = (const float*)d_in[3];
  const float* item_tables = (const float*)d_in[4];
  const float* sw_table    = (const float*)d_in[5];
  const float* uW1 = (const float*)d_in[6];
  const float* ub1 = (const float*)d_in[7];
  const float* uW2 = (const float*)d_in[8];
  const float* ub2 = (const float*)d_in[9];
  const float* iW1 = (const float*)d_in[10];
  const float* ib1 = (const float*)d_in[11];
  const float* iW2 = (const float*)d_in[12];
  const float* ib2 = (const float*)d_in[13];
  float* out = (float*)d_out;

  // ws layout: bf16 transposed weights only (no U/V round-trip anymore)
  ushort* W1tu = (ushort*)d_ws;             // [256][256] bf16
  ushort* W1ti = W1tu + 256 * 256;          // [256][256]
  ushort* W2tu = W1ti + 256 * 256;          // [128][256]
  ushort* W2ti = W2tu + 128 * 256;          // [128][256]

  prep_kernel<<<768, 256, 0, stream>>>(uW1, uW2, iW1, iW2, W1tu, W2tu, W1ti, W2ti);

  fused_kernel<<<dim3(BATCH / ROWS), 256, 0, stream>>>(
      user_ids, item_ids, sw_ids, user_tables, item_tables, sw_table,
      W1tu, ub1, W2tu, ub2, W1ti, ib1, W2ti, ib2, out);
}

// Round 3
// 213.154 us; speedup vs baseline: 1.0904x; 1.0904x over previous
//
#include <hip/hip_runtime.h>
#include <math.h>

#define BATCH 4096
#define NFEAT 4
#define VOCAB 100000
#define EMB 64
#define D_IN 256
#define D_H 256
#define D_O 128
#define ROWS 16            // rows per tower block
#define XS_STRIDE 264      // ushort stride for 256-wide bf16 rows (+8 pad -> 2-way only)
#define YS_STRIDE 132      // float stride for 128-wide fp32 rows

typedef __attribute__((ext_vector_type(8))) short bf16x8;
typedef __attribute__((ext_vector_type(4))) float f32x4;

__device__ inline ushort f2bf(float f) {
  union { float f; unsigned u; } v; v.f = f;
  unsigned u = v.u;
  return (ushort)((u + 0x7fffu + ((u >> 16) & 1u)) >> 16);  // RNE
}

// ---------------------------------------------------------------------------
// Prep: transpose + convert weights to bf16 Wt[n][k] via 32x32 LDS tiles.
// Coalesced float4 reads, coalesced ushort4 writes (old version was
// stride-1KB scalar reads -> ~25 MB of cold-line over-fetch).
// Block b -> (matrix, 32x32 tile). 192 blocks, 256 threads.
// ---------------------------------------------------------------------------
__global__ __launch_bounds__(256) void prep_kernel(
    const float* __restrict__ uW1, const float* __restrict__ uW2,
    const float* __restrict__ iW1, const float* __restrict__ iW2,
    ushort* __restrict__ W1tu, ushort* __restrict__ W2tu,
    ushort* __restrict__ W1ti, ushort* __restrict__ W2ti) {
  __shared__ __align__(16) ushort T[32 * 36];  // [n_local][k_local], stride 36
  const int b = blockIdx.x, tid = threadIdx.x;
  const float* src; ushort* dst; int N; int t;
  if (b < 64)       { src = uW1; dst = W1tu; N = 256; t = b; }
  else if (b < 128) { src = iW1; dst = W1ti; N = 256; t = b - 64; }
  else if (b < 160) { src = uW2; dst = W2tu; N = 128; t = b - 128; }
  else              { src = iW2; dst = W2ti; N = 128; t = b - 160; }
  int kt, nt;
  if (N == 256) { kt = t >> 3; nt = t & 7; }   // 8x8 tiles of 32x32
  else          { kt = t >> 2; nt = t & 3; }   // 8x4 tiles
  const int k0 = kt * 32, n0 = nt * 32;
  {
    int r = tid >> 3, c4 = tid & 7;            // row k0+r, cols n0+c4*4..+3
    float4 v = *(const float4*)&src[(size_t)(k0 + r) * N + n0 + c4 * 4];
    T[(c4 * 4 + 0) * 36 + r] = f2bf(v.x);
    T[(c4 * 4 + 1) * 36 + r] = f2bf(v.y);
    T[(c4 * 4 + 2) * 36 + r] = f2bf(v.z);
    T[(c4 * 4 + 3) * 36 + r] = f2bf(v.w);
  }
  __syncthreads();
  {
    int orow = tid >> 3, oc4 = tid & 7;        // out row n0+orow, k k0+oc4*4
    ushort4 o = *(const ushort4*)&T[orow * 36 + oc4 * 4];
    *(ushort4*)&dst[(size_t)(n0 + orow) * 256 + k0 + oc4 * 4] = o;
  }
}

// ---------------------------------------------------------------------------
// Fused tower, bf16 MFMA: gather -> L1(256->256 relu) -> L2(256->128 relu)
// -> row L2-normalize -> global U/V (fp32).
// Grid (BATCH/ROWS, 2), 256 threads (4 waves). MFMA 16x16x32:
//   A-frag: lane holds A[m=lane&15][k=quad*8+j]
//   B-frag: lane holds B[k=quad*8+j][n=lane&15]  (read from Wt[n][k] contiguously)
//   C/D   : lane holds D[row=quad*4+reg][col=lane&15]
// (byte-identical to the 217.7 us round-0 version)
// ---------------------------------------------------------------------------
__global__ __launch_bounds__(256) void tower_kernel(
    const int* __restrict__ user_ids, const int* __restrict__ item_ids,
    const float* __restrict__ user_tables, const float* __restrict__ item_tables,
    const ushort* __restrict__ W1tu, const float* __restrict__ ub1,
    const ushort* __restrict__ W2tu, const float* __restrict__ ub2,
    const ushort* __restrict__ W1ti, const float* __restrict__ ib1,
    const ushort* __restrict__ W2ti, const float* __restrict__ ib2,
    float* __restrict__ U, float* __restrict__ V) {
  const int tower = blockIdx.y;
  const int* ids = tower ? item_ids : user_ids;
  const float* tab = tower ? item_tables : user_tables;
  const ushort* W1t = tower ? W1ti : W1tu;
  const float* b1 = tower ? ib1 : ub1;
  const ushort* W2t = tower ? W2ti : W2tu;
  const float* b2 = tower ? ib2 : ub2;
  float* O = tower ? V : U;

  const int r0 = blockIdx.x * ROWS;
  const int tid = threadIdx.x;

  __shared__ ushort Xs[ROWS][XS_STRIDE];
  __shared__ ushort Hs[ROWS][XS_STRIDE];
  __shared__ float Ys[ROWS][YS_STRIDE];

  // ---- gather + bf16 convert: 16 rows x 64 float4 slots, 4 per thread ----
#pragma unroll
  for (int i = 0; i < 4; i++) {
    int slot = i * 256 + tid;
    int row = slot >> 6;
    int c4 = slot & 63;
    int f = c4 >> 4;
    int id = ids[(size_t)(r0 + row) * NFEAT + f];
    float4 v = ((const float4*)(tab + ((size_t)f * VOCAB + (size_t)id) * EMB))[c4 & 15];
    ushort4 o = {f2bf(v.x), f2bf(v.y), f2bf(v.z), f2bf(v.w)};
    *(ushort4*)&Xs[row][c4 * 4] = o;
  }
  __syncthreads();

  const int lane = tid & 63;
  const int w = tid >> 6;
  const int m = lane & 15;
  const int quad = lane >> 4;

  // ---- layer 1: Hs[16][256] = relu(Xs @ W1 + b1), wave w -> cols w*64..+63
  {
    bf16x8 a[8];
#pragma unroll
    for (int k0 = 0; k0 < 8; k0++)
      a[k0] = *(const bf16x8*)&Xs[m][k0 * 32 + quad * 8];
#pragma unroll
    for (int ct = 0; ct < 4; ct++) {
      int n = (w * 4 + ct) * 16 + m;
      const ushort* wp = W1t + (size_t)n * 256 + quad * 8;
      f32x4 acc = {0.f, 0.f, 0.f, 0.f};
#pragma unroll
      for (int k0 = 0; k0 < 8; k0++)
        acc = __builtin_amdgcn_mfma_f32_16x16x32_bf16(
            a[k0], *(const bf16x8*)(wp + k0 * 32), acc, 0, 0, 0);
      float bias = b1[n];
#pragma unroll
      for (int reg = 0; reg < 4; reg++) {
        int r = quad * 4 + reg;
        Hs[r][n] = f2bf(fmaxf(acc[reg] + bias, 0.f));
      }
    }
  }
  __syncthreads();

  // ---- layer 2: Ys[16][128] = relu(Hs @ W2 + b2), wave w -> cols w*32..+31
  {
    bf16x8 h[8];
#pragma unroll
    for (int k0 = 0; k0 < 8; k0++)
      h[k0] = *(const bf16x8*)&Hs[m][k0 * 32 + quad * 8];
#pragma unroll
    for (int ct = 0; ct < 2; ct++) {
      int n = (w * 2 + ct) * 16 + m;
      const ushort* wp = W2t + (size_t)n * 256 + quad * 8;
      f32x4 acc = {0.f, 0.f, 0.f, 0.f};
#pragma unroll
      for (int k0 = 0; k0 < 8; k0++)
        acc = __builtin_amdgcn_mfma_f32_16x16x32_bf16(
            h[k0], *(const bf16x8*)(wp + k0 * 32), acc, 0, 0, 0);
      float bias = b2[n];
#pragma unroll
      for (int reg = 0; reg < 4; reg++) {
        int r = quad * 4 + reg;
        Ys[r][n] = fmaxf(acc[reg] + bias, 0.f);
      }
    }
  }
  __syncthreads();

  // ---- row L2-normalize, 4 rows per wave, write fp32 U/V ----
#pragma unroll
  for (int rr = 0; rr < 4; rr++) {
    int row = w * 4 + rr;
    float y0 = Ys[row][lane];
    float y1 = Ys[row][64 + lane];
    float s = y0 * y0 + y1 * y1;
#pragma unroll
    for (int off = 32; off; off >>= 1) s += __shfl_xor(s, off);
    float inv = 1.f / fmaxf(sqrtf(s), 1e-8f);
    float* op = O + (size_t)(r0 + row) * D_O;
    op[lane] = y0 * inv;
    op[64 + lane] = y1 * inv;
  }
}

// ---------------------------------------------------------------------------
// Scores on pre-normalized U,V. Block = 4 user rows i0..i0+3; the 7 shared
// V rows (cols i0..i0+6 mod B) and their log(sw) are staged in LDS once
// (old version reloaded each V row 4x from global + 16 serial logf gathers).
// ---------------------------------------------------------------------------
__global__ __launch_bounds__(256) void score_kernel(
    const float* __restrict__ U, const float* __restrict__ V,
    const int* __restrict__ sw_ids, const float* __restrict__ sw_table,
    float* __restrict__ out) {
  __shared__ float Vs[7][132];
  __shared__ float lsw[8];
  const int tid = threadIdx.x;
  const int i0 = blockIdx.x * 4;

  if (tid < 224) {                       // 7 rows x 32 float4
    int s = tid >> 5, c4 = tid & 31;
    int c = (i0 + s) & (BATCH - 1);
    float4 v = ((const float4*)(V + (size_t)c * D_O))[c4];
    *(float4*)&Vs[s][c4 * 4] = v;
  } else if (tid < 231) {
    int s = tid - 224;
    int c = (i0 + s) & (BATCH - 1);
    lsw[s] = logf(sw_table[sw_ids[c]]);
  }
  __syncthreads();

  const int wv = tid >> 6, lane = tid & 63;
  const int i = i0 + wv;
  float u0 = U[(size_t)i * D_O + lane];
  float u1 = U[(size_t)i * D_O + 64 + lane];
#pragma unroll
  for (int j = 0; j < 4; j++) {
    float v0 = Vs[wv + j][lane];
    float v1 = Vs[wv + j][64 + lane];
    float d = u0 * v0 + u1 * v1;
#pragma unroll
    for (int off = 32; off; off >>= 1) d += __shfl_xor(d, off);
    if (lane == 0) out[(size_t)i * 4 + j] = d - lsw[wv + j];
  }
}

extern "C" void kernel_launch(void* const* d_in, const int* in_sizes, int n_in,
                              void* d_out, int out_size, void* d_ws, size_t ws_size,
                              hipStream_t stream) {
  (void)in_sizes; (void)n_in; (void)out_size; (void)ws_size;
  const int*   user_ids    = (const int*)d_in[0];
  const int*   item_ids    = (const int*)d_in[1];
  const int*   sw_ids      = (const int*)d_in[2];
  const float* user_tables = (const float*)d_in[3];
  const float* item_tables = (const float*)d_in[4];
  const float* sw_table    = (const float*)d_in[5];
  const float* uW1 = (const float*)d_in[6];
  const float* ub1 = (const float*)d_in[7];
  const float* uW2 = (const float*)d_in[8];
  const float* ub2 = (const float*)d_in[9];
  const float* iW1 = (const float*)d_in[10];
  const float* ib1 = (const float*)d_in[11];
  const float* iW2 = (const float*)d_in[12];
  const float* ib2 = (const float*)d_in[13];
  float* out = (float*)d_out;

  // ws layout
  float* U = (float*)d_ws;                            // [B,128] fp32
  float* V = U + (size_t)BATCH * D_O;                 // [B,128] fp32
  ushort* W1tu = (ushort*)(V + (size_t)BATCH * D_O);  // [256][256] bf16
  ushort* W1ti = W1tu + 256 * 256;                    // [256][256]
  ushort* W2tu = W1ti + 256 * 256;                    // [128][256]
  ushort* W2ti = W2tu + 128 * 256;                    // [128][256]

  prep_kernel<<<192, 256, 0, stream>>>(uW1, uW2, iW1, iW2, W1tu, W2tu, W1ti, W2ti);

  tower_kernel<<<dim3(BATCH / ROWS, 2), 256, 0, stream>>>(
      user_ids, item_ids, user_tables, item_tables,
      W1tu, ub1, W2tu, ub2, W1ti, ib1, W2ti, ib2, U, V);

  score_kernel<<<BATCH / 4, 256, 0, stream>>>(U, V, sw_ids, sw_table, out);
}